// Round 1
// baseline (1468.615 us; speedup 1.0000x reference)
//
#include <hip/hip_runtime.h>
#include <math.h>

#define BLK 256
constexpr float CC   = 1.2f;
constexpr float SQC  = 1.09544511501033215f;      // sqrt(1.2)
constexpr float MAXN = (1.0f - 4e-3f) / SQC;      // geoopt projx maxnorm
constexpr float MINN = 1e-15f;

// ---------------- LDS layout (floats) ----------------
constexpr int OF_BE1 = 0;        // 80
constexpr int OF_BE2 = 80;       // 104
constexpr int OF_BE3 = 184;      // 128
constexpr int OF_EB1 = 312;      // 80   expmap0(bh1)
constexpr int OF_EB2 = 392;      // 104
constexpr int OF_EB3 = 496;      // 128
constexpr int OF_EBA = 624;      // 128  expmap0(bah)
constexpr int OF_U1  = 752;      // 128  Wae^T wte
constexpr int OF_U2  = 880;      // 128  Wae^T wth
constexpr int OF_WTE = 1008;     // 128
constexpr int OF_WTH = 1136;     // 128
constexpr int OF_SC  = 1264;     // 16: c1,c2,y2h1,y2h2,y2h3,y2ah,EBW1,EBW2,bte,bth
constexpr int OF_BF1 = 1280;     // 10
constexpr int OF_BF2 = 1290;     // 10
constexpr int OF_NIN = 1300;     // 64 per-token norm chain
constexpr int OF_SC0 = 1364;     // 64 expmap0 scale of x0
constexpr int OF_D1  = 1428;     // 64 out_e . u1
constexpr int OF_D2  = 1492;     // 64 out_e . u2
constexpr int OF_OVEC= 1556;     // 256 pooled vector
constexpr int OF_OUTH= 1824;     // 64x128
constexpr int OF_OUTE= 10016;    // 64x128
constexpr int OF_SCR = 18208;    // scratch pool
constexpr int SS     = 20512;    // scratch size
constexpr int TOT    = OF_SCR + SS;   // 38720 floats = 154880 B

// scratch-relative offsets
constexpr int SX0 = 0;       // 64x36 token inputs
constexpr int SW1 = 2304;    // layer-1 weights (80x36)
constexpr int SW  = 0;       // big weights (up to 128x132 = 16896)
constexpr int SL1 = 8736;    // 64x80 layer-1 out
constexpr int SL2 = 13856;   // 64x104 layer-2 out

__device__ __forceinline__ float wsum(float v){
#pragma unroll
  for(int i=32;i>0;i>>=1) v += __shfl_xor(v, i, 64);
  return v;
}
__device__ __forceinline__ float artanh_c(float x){
  x = fminf(fmaxf(x, -0.9999999f), 0.9999999f);
  return 0.5f * logf((1.0f + x) / (1.0f - x));
}
__device__ __forceinline__ float tanh_c(float x){
  return tanhf(fminf(fmaxf(x, -15.0f), 15.0f));
}

// ---------------- setup kernel: folded constants into ws ----------------
// ws layout: [0..127] u1, [128..255] u2, [256..335] ebh1, [336..439] ebh2,
// [440..567] ebh3, [568..695] ebah, [696] c1 [697] c2 [698..701] y2h1..y2ah
// [702] EBW1 [703] EBW2
__global__ void k_setup(const float* __restrict__ Wae, const float* __restrict__ bae,
                        const float* __restrict__ bh1, const float* __restrict__ bh2,
                        const float* __restrict__ bh3, const float* __restrict__ bah,
                        const float* __restrict__ Wte, const float* __restrict__ Wth,
                        float* __restrict__ ws){
  const int tid = threadIdx.x;            // 256 threads, 1 block
  {
    const int which = tid >> 7, k = tid & 127;
    const float* wv = which ? Wth : Wte;
    float s = 0.f;
#pragma unroll 4
    for(int j=0;j<128;++j) s += Wae[j*128+k] * wv[j];
    ws[which*128 + k] = s;
  }
  if(tid < 64){
    const int l = tid;
    float p1=0.f, p2=0.f;
    for(int j=l;j<128;j+=64){ p1 += bae[j]*Wte[j]; p2 += bae[j]*Wth[j]; }
    p1 = wsum(p1); p2 = wsum(p2);
    if(l==0){ ws[696]=p1; ws[697]=p2; }
    const float* bs[4] = {bh1,bh2,bh3,bah};
    const int dims[4]  = {80,104,128,128};
    const int offs[4]  = {256,336,440,568};
    for(int v=0;v<4;++v){
      const float* bp = bs[v]; const int D = dims[v];
      float q = 0.f;
      for(int j=l;j<D;j+=64) q += bp[j]*bp[j];
      q = wsum(q);
      float nb = fmaxf(sqrtf(q), MINN);
      float th = tanh_c(SQC*nb);
      float coef = th/(SQC*nb);
      float ne = th/SQC;
      if(ne > MAXN){ coef *= MAXN/ne; ne = MAXN; }
      for(int j=l;j<D;j+=64) ws[offs[v]+j] = coef*bp[j];
      if(l==0) ws[698+v] = ne*ne;
      if(v==3){
        float e1=0.f, e2=0.f;
        for(int j=l;j<D;j+=64){ e1 += bp[j]*Wte[j]; e2 += bp[j]*Wth[j]; }
        e1 = wsum(e1)*coef; e2 = wsum(e2)*coef;
        if(l==0){ ws[702]=e1; ws[703]=e2; }
      }
    }
  }
}

// ---------------- helpers for main kernel ----------------
template<int K, int Kp, int OUT>
__device__ __forceinline__ void stage_w(float* __restrict__ dst, const float* __restrict__ src, int tid){
  constexpr int Kq = K >> 2;
  constexpr int n4 = OUT * Kq;
  for(int i=tid;i<n4;i+=BLK){
    const int j  = i / Kq;
    const int k4 = i - j*Kq;
    float4 v = ((const float4*)src)[i];
    *(float4*)(dst + j*Kp + (k4<<2)) = v;
  }
}

template<int K,int Kp,int OUT,int INS>
__device__ __forceinline__ void mv_group(const float* __restrict__ Wl,
                                         const float* __restrict__ Xin,
                                         int t0, int lane, float a0[8], float a1[8]){
  const int j0 = lane;
  const int j1 = (lane + 64 < OUT) ? lane + 64 : 0;
  const float* w0p = Wl + j0*Kp;
  const float* w1p = Wl + j1*Kp;
#pragma unroll
  for(int u=0;u<8;++u){ a0[u]=0.f; a1[u]=0.f; }
#pragma unroll 4
  for(int k=0;k<K;k+=4){
    float4 w0 = *(const float4*)(w0p+k);
    float4 w1 = *(const float4*)(w1p+k);
#pragma unroll
    for(int u=0;u<8;++u){
      float4 xv = *(const float4*)(Xin + (t0+u)*INS + k);
      a0[u] = fmaf(w0.w,xv.w, fmaf(w0.z,xv.z, fmaf(w0.y,xv.y, fmaf(w0.x,xv.x, a0[u]))));
      a1[u] = fmaf(w1.w,xv.w, fmaf(w1.z,xv.z, fmaf(w1.y,xv.y, fmaf(w1.x,xv.x, a1[u]))));
    }
  }
}

// p_linear epilogue (mobius matvec + mobius bias add + projx [+ mob_relu])
template<bool SC_IN, bool MRELU>
__device__ __forceinline__ void hyper_epi(float* lds, int t, int lane, int OUT,
    float m0, float m1, const float* __restrict__ eb, float y2,
    float* __restrict__ outp, int outs){
  const int j0 = lane;
  const bool a1 = (lane + 64) < OUT;
  const int j1 = a1 ? lane + 64 : 0;
  if(SC_IN){ float sc = lds[OF_SC0+t]; m0 *= sc; m1 *= sc; }
  if(!a1) m1 = 0.f;
  float xn  = fmaxf(lds[OF_NIN+t], MINN);
  float m2  = wsum(m0*m0 + m1*m1);
  float meb = wsum(m0*eb[j0] + m1*eb[j1]);
  float mxn = fmaxf(sqrtf(m2), MINN);
  float r   = artanh_c(SQC*xn);
  float s   = tanh_c(mxn/xn*r)/(mxn*SQC);
  float nr  = s*mxn;
  if(nr > MAXN){ s *= MAXN/nr; nr = MAXN; }
  float xy = s*meb, x2 = nr*nr;
  float den = fmaxf(1.f + 2.f*CC*xy + CC*CC*x2*y2, MINN);
  float A  = (1.f + 2.f*CC*xy + CC*y2)/den;
  float Bc = (1.f - CC*x2)/den;
  float n3 = sqrtf(fmaxf(A*A*x2 + 2.f*A*Bc*xy + Bc*Bc*y2, 0.f));
  float rho = (n3 > MAXN) ? MAXN/n3 : 1.f;
  float nv  = fminf(n3, MAXN);
  float ca = rho*A*s, cb = rho*Bc;
  float v0 = ca*m0 + cb*eb[j0];
  float v1 = ca*m1 + cb*eb[j1];
  if(MRELU){
    float nvc = fmaxf(nv, MINN);
    float lam = artanh_c(SQC*nvc)/(SQC*nvc);
    float r0 = fmaxf(lam*v0, 0.f);
    float r1 = a1 ? fmaxf(lam*v1, 0.f) : 0.f;
    float rn = fmaxf(sqrtf(wsum(r0*r0 + r1*r1)), MINN);
    float th = tanh_c(SQC*rn);
    float tau = th/(SQC*rn);
    float nf  = th/SQC;
    if(nf > MAXN){ tau *= MAXN/nf; nf = MAXN; }
    v0 = tau*r0; v1 = tau*r1; nv = nf;
  }
  outp[t*outs + j0] = v0;
  if(a1) outp[t*outs + j1] = v1;
  if(lane==0) lds[OF_NIN+t] = nv;
}

template<bool DOTS>
__device__ __forceinline__ void euc_epi(float* lds, int t, int lane, int OUT,
    float m0, float m1, const float* __restrict__ be,
    float* __restrict__ outp, int outs){
  const int j0 = lane;
  const bool a1 = (lane + 64) < OUT;
  const int j1 = a1 ? lane + 64 : 0;
  float v0 = fmaxf(m0 + be[j0], 0.f);
  float v1 = a1 ? fmaxf(m1 + be[j1], 0.f) : 0.f;
  outp[t*outs + j0] = v0;
  if(a1) outp[t*outs + j1] = v1;
  if(DOTS){
    float d1 = wsum(v0*lds[OF_U1+j0] + v1*lds[OF_U1+j1]);
    float d2 = wsum(v0*lds[OF_U2+j0] + v1*lds[OF_U2+j1]);
    if(lane==0){ lds[OF_D1+t]=d1; lds[OF_D2+t]=d2; }
  }
}

// ---------------- main fused kernel: one block per batch row ----------------
__global__ __launch_bounds__(BLK, 1) void k_main(
    const float* __restrict__ x,
    const float* __restrict__ We1, const float* __restrict__ be1,
    const float* __restrict__ We2, const float* __restrict__ be2,
    const float* __restrict__ We3, const float* __restrict__ be3,
    const float* __restrict__ Wh1, const float* __restrict__ Wh2, const float* __restrict__ Wh3,
    const float* __restrict__ Wah,
    const float* __restrict__ Wte, const float* __restrict__ bte,
    const float* __restrict__ Wth, const float* __restrict__ bth,
    const float* __restrict__ Wf1, const float* __restrict__ bf1,
    const float* __restrict__ Wf2, const float* __restrict__ bf2,
    const float* __restrict__ ws, float* __restrict__ out){
  extern __shared__ float lds[];
  const int tid = threadIdx.x, lane = tid & 63, w = tid >> 6, b = blockIdx.x;
  float* scr = lds + OF_SCR;

  // ---- stage constants ----
  for(int i=tid;i<80;i+=BLK){ lds[OF_BE1+i]=be1[i]; lds[OF_EB1+i]=ws[256+i]; }
  for(int i=tid;i<104;i+=BLK){ lds[OF_BE2+i]=be2[i]; lds[OF_EB2+i]=ws[336+i]; }
  for(int i=tid;i<128;i+=BLK){
    lds[OF_BE3+i]=be3[i]; lds[OF_EB3+i]=ws[440+i]; lds[OF_EBA+i]=ws[568+i];
    lds[OF_U1+i]=ws[i];   lds[OF_U2+i]=ws[128+i];
    lds[OF_WTE+i]=Wte[i]; lds[OF_WTH+i]=Wth[i];
  }
  if(tid<8)  lds[OF_SC+tid]=ws[696+tid];
  if(tid==8) lds[OF_SC+8]=bte[0];
  if(tid==9) lds[OF_SC+9]=bth[0];
  for(int i=tid;i<10;i+=BLK){ lds[OF_BF1+i]=bf1[i]; lds[OF_BF2+i]=bf2[i]; }

  float accE0=0.f, accE1=0.f, accH0=0.f, accH1=0.f;

  for(int st=0; st<2; ++st){
    const int s0 = st*64;
    __syncthreads();
    // ---- load X0 (transpose x[b,:,s0:s0+64] -> [tok][chan]) + stage Wh1 ----
#pragma unroll
    for(int r=0;r<8;++r){
      int c = w*8 + r;
      scr[SX0 + lane*36 + c] = x[((size_t)(b*32 + c))*128 + s0 + lane];
    }
    stage_w<32,36,80>(scr+SW1, Wh1, tid);
    __syncthreads();
    // ---- per-token expmap0 scalars (wave-local tokens) ----
    for(int i=0;i<16;++i){
      int t = w*16 + i;
      float v = (lane < 32) ? scr[SX0 + t*36 + lane] : 0.f;
      float n2 = wsum(v*v);
      if(lane==0){
        float n0 = fmaxf(sqrtf(n2), MINN);
        float th = tanh_c(SQC*n0);
        float nh = th/SQC;
        float scl = th/(SQC*n0);
        if(nh > MAXN){ scl *= MAXN/nh; nh = MAXN; }
        lds[OF_NIN+t]=nh; lds[OF_SC0+t]=scl;
      }
    }
    // ---- H1 ----
    for(int g=0;g<2;++g){
      int t0 = w*16 + g*8; float a0[8], a1v[8];
      mv_group<32,36,80,36>(scr+SW1, scr+SX0, t0, lane, a0, a1v);
      for(int u=0;u<8;++u)
        hyper_epi<true,true>(lds, t0+u, lane, 80, a0[u], a1v[u], lds+OF_EB1, lds[OF_SC+2], scr+SL1, 80);
    }
    __syncthreads();
    stage_w<80,84,104>(scr+SW, Wh2, tid);
    __syncthreads();
    // ---- H2 ----
    for(int g=0;g<2;++g){
      int t0 = w*16 + g*8; float a0[8], a1v[8];
      mv_group<80,84,104,80>(scr+SW, scr+SL1, t0, lane, a0, a1v);
      for(int u=0;u<8;++u)
        hyper_epi<false,true>(lds, t0+u, lane, 104, a0[u], a1v[u], lds+OF_EB2, lds[OF_SC+3], scr+SL2, 104);
    }
    __syncthreads();
    stage_w<104,108,128>(scr+SW, Wh3, tid);
    __syncthreads();
    // ---- H3 -> out_h (no mob_relu) ----
    for(int g=0;g<2;++g){
      int t0 = w*16 + g*8; float a0[8], a1v[8];
      mv_group<104,108,128,104>(scr+SW, scr+SL2, t0, lane, a0, a1v);
      for(int u=0;u<8;++u)
        hyper_epi<false,false>(lds, t0+u, lane, 128, a0[u], a1v[u], lds+OF_EB3, lds[OF_SC+4], lds+OF_OUTH, 128);
    }
    __syncthreads();
    // ---- reload X0 (was clobbered by W staging) + stage We1 ----
#pragma unroll
    for(int r=0;r<8;++r){
      int c = w*8 + r;
      scr[SX0 + lane*36 + c] = x[((size_t)(b*32 + c))*128 + s0 + lane];
    }
    stage_w<32,36,80>(scr+SW1, We1, tid);
    __syncthreads();
    // ---- E1 ----
    for(int g=0;g<2;++g){
      int t0 = w*16 + g*8; float a0[8], a1v[8];
      mv_group<32,36,80,36>(scr+SW1, scr+SX0, t0, lane, a0, a1v);
      for(int u=0;u<8;++u)
        euc_epi<false>(lds, t0+u, lane, 80, a0[u], a1v[u], lds+OF_BE1, scr+SL1, 80);
    }
    __syncthreads();
    stage_w<80,84,104>(scr+SW, We2, tid);
    __syncthreads();
    // ---- E2 ----
    for(int g=0;g<2;++g){
      int t0 = w*16 + g*8; float a0[8], a1v[8];
      mv_group<80,84,104,80>(scr+SW, scr+SL1, t0, lane, a0, a1v);
      for(int u=0;u<8;++u)
        euc_epi<false>(lds, t0+u, lane, 104, a0[u], a1v[u], lds+OF_BE2, scr+SL2, 104);
    }
    __syncthreads();
    stage_w<104,108,128>(scr+SW, We3, tid);
    __syncthreads();
    // ---- E3 -> out_e + folded attention dots ----
    for(int g=0;g<2;++g){
      int t0 = w*16 + g*8; float a0[8], a1v[8];
      mv_group<104,108,128,104>(scr+SW, scr+SL2, t0, lane, a0, a1v);
      for(int u=0;u<8;++u)
        euc_epi<true>(lds, t0+u, lane, 128, a0[u], a1v[u], lds+OF_BE3, lds+OF_OUTE, 128);
    }
    __syncthreads();
    stage_w<128,132,128>(scr+SW, Wah, tid);
    __syncthreads();
    // ---- attention + pooling accumulate ----
    for(int g=0;g<2;++g){
      int t0 = w*16 + g*8; float a0[8], a1v[8];
      mv_group<128,132,128,128>(scr+SW, lds+OF_OUTH, t0, lane, a0, a1v);
      for(int u=0;u<8;++u){
        const int t = t0+u;
        const int j0 = lane, j1 = lane+64;
        float m0 = a0[u], m1 = a1v[u];
        float m2  = wsum(m0*m0 + m1*m1);
        float mw1 = wsum(m0*lds[OF_WTE+j0] + m1*lds[OF_WTE+j1]);
        float mw2 = wsum(m0*lds[OF_WTH+j0] + m1*lds[OF_WTH+j1]);
        float meb = wsum(m0*lds[OF_EBA+j0] + m1*lds[OF_EBA+j1]);
        float xn  = fmaxf(lds[OF_NIN+t], MINN);
        float y2  = lds[OF_SC+5];
        float mxn = fmaxf(sqrtf(m2), MINN);
        float rr  = artanh_c(SQC*xn);
        float s   = tanh_c(mxn/xn*rr)/(mxn*SQC);
        float nr  = s*mxn;
        if(nr > MAXN){ s *= MAXN/nr; nr = MAXN; }
        float xy = s*meb, x2 = nr*nr;
        float den = fmaxf(1.f + 2.f*CC*xy + CC*CC*x2*y2, MINN);
        float A  = (1.f + 2.f*CC*xy + CC*y2)/den;
        float Bc = (1.f - CC*x2)/den;
        float n3 = sqrtf(fmaxf(A*A*x2 + 2.f*A*Bc*xy + Bc*Bc*y2, 0.f));
        float rho = (n3 > MAXN) ? MAXN/n3 : 1.f;
        float nv  = fminf(n3, MAXN);
        float nvc = fmaxf(nv, MINN);
        float lam = artanh_c(SQC*nvc)/(SQC*nvc);
        float lr = lam*rho;
        float th_wte = lr*(A*s*mw1 + Bc*lds[OF_SC+6]);
        float th_wth = lr*(A*s*mw2 + Bc*lds[OF_SC+7]);
        float te_wte = lds[OF_D1+t] + lds[OF_SC+0];
        float te_wth = lds[OF_D2+t] + lds[OF_SC+1];
        float a_e = 0.5f*(te_wte - th_wte) + lds[OF_SC+8];
        float a_h = 0.5f*(th_wth - te_wth) + lds[OF_SC+9];
        float mx_ = fmaxf(a_e, a_h);
        float ee = expf(a_e - mx_), eh = expf(a_h - mx_);
        float inv = 1.f/(ee + eh);
        float wge = ee*inv, wgh = eh*inv;
        // mobius scalar mul by wgh then logmap0 -> scalar g on out_h
        float inner = wgh * rr;                 // rr = artanh(sqc*|out_h|)
        float scl = tanh_c(inner)/(xn*SQC);
        float nn = scl*xn;
        if(nn > MAXN){ scl *= MAXN/nn; nn = MAXN; }
        float nnc = fmaxf(nn, MINN);
        float lam2 = artanh_c(SQC*nnc)/(SQC*nnc);
        float g2 = lam2*scl;
        accE0 += wge * lds[OF_OUTE + t*128 + j0];
        accE1 += wge * lds[OF_OUTE + t*128 + j1];
        accH0 += g2  * lds[OF_OUTH + t*128 + j0];
        accH1 += g2  * lds[OF_OUTH + t*128 + j1];
      }
    }
  } // tile loop

  // ---- cross-wave pooling combine + classifier ----
  __syncthreads();
  scr[w*256 + lane]        = accE0;
  scr[w*256 + 64 + lane]   = accE1;
  scr[1024 + w*256 + lane]      = accH0;
  scr[1024 + w*256 + 64 + lane] = accH1;
  __syncthreads();
  if(w == 0){
#pragma unroll
    for(int part=0; part<4; ++part){
      int j = lane + 64*(part & 1);
      int base = (part >> 1)*1024;
      float s_ = scr[base+j] + scr[base+256+j] + scr[base+512+j] + scr[base+768+j];
      lds[OF_OVEC + (part>>1)*128 + j] = s_ * (1.f/128.f);
    }
    float f1v[10];
#pragma unroll
    for(int i=0;i<10;++i){
      float p = 0.f;
#pragma unroll
      for(int m=0;m<4;++m){ int k = lane + 64*m; p += Wf1[i*256+k]*lds[OF_OVEC+k]; }
      f1v[i] = fmaxf(wsum(p) + lds[OF_BF1+i], 0.f);
    }
    if(lane < 10){
      float o2 = lds[OF_BF2+lane];
#pragma unroll
      for(int k=0;k<10;++k) o2 += Wf2[lane*10+k]*f1v[k];
      out[b*10 + lane] = o2;
    }
  }
}

extern "C" void kernel_launch(void* const* d_in, const int* in_sizes, int n_in,
                              void* d_out, int out_size, void* d_ws, size_t ws_size,
                              hipStream_t stream){
  (void)in_sizes; (void)n_in; (void)out_size; (void)ws_size;
  const float* x   = (const float*)d_in[0];
  const float* We1 = (const float*)d_in[1];
  const float* be1 = (const float*)d_in[2];
  const float* We2 = (const float*)d_in[3];
  const float* be2 = (const float*)d_in[4];
  const float* We3 = (const float*)d_in[5];
  const float* be3 = (const float*)d_in[6];
  const float* Wh1 = (const float*)d_in[7];
  const float* bh1 = (const float*)d_in[8];
  const float* Wh2 = (const float*)d_in[9];
  const float* bh2 = (const float*)d_in[10];
  const float* Wh3 = (const float*)d_in[11];
  const float* bh3 = (const float*)d_in[12];
  const float* Wae = (const float*)d_in[13];
  const float* bae = (const float*)d_in[14];
  const float* Wah = (const float*)d_in[15];
  const float* bah = (const float*)d_in[16];
  const float* Wte = (const float*)d_in[17];
  const float* bte = (const float*)d_in[18];
  const float* Wth = (const float*)d_in[19];
  const float* bth = (const float*)d_in[20];
  const float* Wf1 = (const float*)d_in[21];
  const float* bf1 = (const float*)d_in[22];
  const float* Wf2 = (const float*)d_in[23];
  const float* bf2 = (const float*)d_in[24];
  float* ws  = (float*)d_ws;
  float* out = (float*)d_out;

  hipLaunchKernelGGL(k_setup, dim3(1), dim3(BLK), 0, stream,
                     Wae, bae, bh1, bh2, bh3, bah, Wte, Wth, ws);

  hipFuncSetAttribute((const void*)k_main,
                      hipFuncAttributeMaxDynamicSharedMemorySize, TOT*4);
  hipLaunchKernelGGL(k_main, dim3(1024), dim3(BLK), TOT*4, stream,
                     x, We1,be1, We2,be2, We3,be3, Wh1,Wh2,Wh3, Wah,
                     Wte,bte, Wth,bth, Wf1,bf1, Wf2,bf2, ws, out);
}

// Round 2
// 1220.500 us; speedup vs baseline: 1.2033x; 1.2033x over previous
//
#include <hip/hip_runtime.h>
#include <math.h>

constexpr float CC   = 1.2f;
constexpr float SQC  = 1.09544511501033215f;      // sqrt(1.2)
constexpr float MAXN = (1.0f - 4e-3f) / SQC;      // geoopt projx maxnorm
constexpr float MINN = 1e-15f;

// ---------------- fast per-lane scalar math ----------------
__device__ __forceinline__ float art_(float x){
  x = fminf(fmaxf(x, -0.9999999f), 0.9999999f);
  return 0.5f * __logf((1.0f + x) / (1.0f - x));
}
__device__ __forceinline__ float tanh_(float x){
  x = fminf(fmaxf(x, -15.0f), 15.0f);
  float e = __expf(2.0f * x);
  return (e - 1.0f) / (e + 1.0f);
}
__device__ __forceinline__ float wsum(float v){
#pragma unroll
  for(int i=32;i>0;i>>=1) v += __shfl_xor(v, i, 64);
  return v;
}

// ---------------- setup kernel: folded constants into ws ----------------
// ws layout: [0..127] u1=Wae^T Wte, [128..255] u2=Wae^T Wth, [256..335] ebh1,
// [336..439] ebh2, [440..567] ebh3, [568..695] ebah, [696] c1 [697] c2
// [698..701] y2h1,y2h2,y2h3,y2ah, [702] EBW1 [703] EBW2.  Park region: ws+1024.
__global__ void k_setup(const float* __restrict__ Wae, const float* __restrict__ bae,
                        const float* __restrict__ bh1, const float* __restrict__ bh2,
                        const float* __restrict__ bh3, const float* __restrict__ bah,
                        const float* __restrict__ Wte, const float* __restrict__ Wth,
                        float* __restrict__ ws){
  const int tid = threadIdx.x;            // 256 threads, 1 block
  {
    const int which = tid >> 7, k = tid & 127;
    const float* wv = which ? Wth : Wte;
    float s = 0.f;
#pragma unroll 4
    for(int j=0;j<128;++j) s += Wae[j*128+k] * wv[j];
    ws[which*128 + k] = s;
  }
  if(tid < 64){
    const int l = tid;
    float p1=0.f, p2=0.f;
    for(int j=l;j<128;j+=64){ p1 += bae[j]*Wte[j]; p2 += bae[j]*Wth[j]; }
    p1 = wsum(p1); p2 = wsum(p2);
    if(l==0){ ws[696]=p1; ws[697]=p2; }
    const float* bs[4] = {bh1,bh2,bh3,bah};
    const int dims[4]  = {80,104,128,128};
    const int offs[4]  = {256,336,440,568};
    for(int v=0;v<4;++v){
      const float* bp = bs[v]; const int D = dims[v];
      float q = 0.f;
      for(int j=l;j<D;j+=64) q += bp[j]*bp[j];
      q = wsum(q);
      float nb = fmaxf(sqrtf(q), MINN);
      float th = tanhf(fminf(fmaxf(SQC*nb,-15.f),15.f));
      float coef = th/(SQC*nb);
      float ne = th/SQC;
      if(ne > MAXN){ coef *= MAXN/ne; ne = MAXN; }
      for(int j=l;j<D;j+=64) ws[offs[v]+j] = coef*bp[j];
      if(l==0) ws[698+v] = ne*ne;
      if(v==3){
        float e1=0.f, e2=0.f;
        for(int j=l;j<D;j+=64){ e1 += bp[j]*Wte[j]; e2 += bp[j]*Wth[j]; }
        e1 = wsum(e1)*coef; e2 = wsum(e2)*coef;
        if(l==0){ ws[702]=e1; ws[703]=e2; }
      }
    }
  }
}

// ---------------- token-per-lane building blocks ----------------
// Raw matvec: out[j] = sum_k W[j][k]*xin[k]; writes raw to buf[j*65+t];
// accumulates m2 = |out|^2 and meb = out . eb.  W/eb indices are lane-invariant
// -> scalar loads (SGPR broadcast).  xin is a compile-time-indexed reg array.
template<int K,int OUT>
__device__ __forceinline__ void mvraw(const float* __restrict__ W, const float* __restrict__ eb,
                                      const float (&xin)[K], float* __restrict__ buf, int t,
                                      float& m2, float& meb){
  for(int jc=0;jc<OUT;jc+=4){
    const float* w0 = W + (size_t)jc*K;
    const float* w1 = w0 + K;
    const float* w2 = w1 + K;
    const float* w3 = w2 + K;
    float a0=0.f,a1=0.f,a2=0.f,a3=0.f;
#pragma unroll
    for(int k=0;k<K;++k){
      const float xv = xin[k];
      a0 = fmaf(w0[k],xv,a0); a1 = fmaf(w1[k],xv,a1);
      a2 = fmaf(w2[k],xv,a2); a3 = fmaf(w3[k],xv,a3);
    }
    buf[(jc+0)*65+t]=a0; buf[(jc+1)*65+t]=a1;
    buf[(jc+2)*65+t]=a2; buf[(jc+3)*65+t]=a3;
    m2  = fmaf(a3,a3,      fmaf(a2,a2,      fmaf(a1,a1,      fmaf(a0,a0,      m2))));
    meb = fmaf(a3,eb[jc+3],fmaf(a2,eb[jc+2],fmaf(a1,eb[jc+1],fmaf(a0,eb[jc+0],meb))));
  }
}

// Euclidean layer: relu(W x + b) -> buf; optionally accumulate dots with u1,u2.
template<int K,int OUT,bool DOTS>
__device__ __forceinline__ void mveuc(const float* __restrict__ W, const float* __restrict__ be,
                                      const float (&xin)[K], float* __restrict__ buf, int t,
                                      const float* __restrict__ u1, const float* __restrict__ u2,
                                      float& d1, float& d2){
  for(int jc=0;jc<OUT;jc+=4){
    const float* w0 = W + (size_t)jc*K;
    const float* w1 = w0 + K;
    const float* w2 = w1 + K;
    const float* w3 = w2 + K;
    float a0=0.f,a1=0.f,a2=0.f,a3=0.f;
#pragma unroll
    for(int k=0;k<K;++k){
      const float xv = xin[k];
      a0 = fmaf(w0[k],xv,a0); a1 = fmaf(w1[k],xv,a1);
      a2 = fmaf(w2[k],xv,a2); a3 = fmaf(w3[k],xv,a3);
    }
    a0 = fmaxf(a0+be[jc+0],0.f); a1 = fmaxf(a1+be[jc+1],0.f);
    a2 = fmaxf(a2+be[jc+2],0.f); a3 = fmaxf(a3+be[jc+3],0.f);
    buf[(jc+0)*65+t]=a0; buf[(jc+1)*65+t]=a1;
    buf[(jc+2)*65+t]=a2; buf[(jc+3)*65+t]=a3;
    if(DOTS){
      d1 = fmaf(a3,u1[jc+3],fmaf(a2,u1[jc+2],fmaf(a1,u1[jc+1],fmaf(a0,u1[jc+0],d1))));
      d2 = fmaf(a3,u2[jc+3],fmaf(a2,u2[jc+2],fmaf(a1,u2[jc+1],fmaf(a0,u2[jc+0],d2))));
    }
  }
}

// Mobius matvec+bias scalar chain: from m2=|mx|^2, meb=mx.eb, input norm xn_in,
// bias norm^2 y2 -> affine coefficients v = ca*mx + cb*eb, result norm nv.
struct HS { float ca, cb, nv; };
__device__ __forceinline__ HS hyper_chain(float m2, float meb, float xn_in, float y2){
  float xn  = fmaxf(xn_in, MINN);
  float mxn = fmaxf(sqrtf(m2), MINN);
  float r   = art_(SQC*xn);
  float s   = tanh_(mxn/xn*r)/(mxn*SQC);
  float nr  = s*mxn;
  if(nr > MAXN){ s *= MAXN/nr; nr = MAXN; }
  float xy = s*meb, x2 = nr*nr;
  float den = fmaxf(1.f + 2.f*CC*xy + CC*CC*x2*y2, MINN);
  float A   = (1.f + 2.f*CC*xy + CC*y2)/den;
  float Bc  = (1.f - CC*x2)/den;
  float n3  = sqrtf(fmaxf(A*A*x2 + 2.f*A*Bc*xy + Bc*Bc*y2, 0.f));
  float rho = (n3 > MAXN) ? MAXN/n3 : 1.f;
  HS h; h.nv = fminf(n3, MAXN); h.ca = rho*A*s; h.cb = rho*Bc;
  return h;
}

// Scale pass with mob_relu: v=ca*raw+cb*eb; r=max(lam*v,0); buf=r; rn2=|r|^2.
template<int OUT>
__device__ __forceinline__ float relu_pass(float* __restrict__ buf, int t,
                                           const float* __restrict__ eb,
                                           float ca, float cb, float lam){
  float rn2 = 0.f;
  for(int j=0;j<OUT;++j){
    float raw = buf[j*65+t];
    float v   = fmaf(ca, raw, cb*eb[j]);
    float r   = fmaxf(lam*v, 0.f);
    rn2 = fmaf(r,r,rn2);
    buf[j*65+t] = r;
  }
  return rn2;
}

// Final H3 pass (no relu): v -> buf and park (stride PSTR).
template<int OUT,int PSTR>
__device__ __forceinline__ void final_pass(float* __restrict__ buf, int t,
                                           const float* __restrict__ eb,
                                           float ca, float cb, float* __restrict__ pk){
  for(int j=0;j<OUT;++j){
    float v = fmaf(ca, buf[j*65+t], cb*eb[j]);
    buf[j*65+t] = v;
    pk[(size_t)j*PSTR + t] = v;
  }
}

template<int K>
__device__ __forceinline__ void loadbuf(float (&xin)[K], const float* __restrict__ buf,
                                        int t, float tau){
#pragma unroll
  for(int k=0;k<K;++k) xin[k] = tau*buf[k*65+t];
}

// ---------------- main kernel: 1 block = 1 wave = one batch row ----------------
// lane = token within the 64-token tile; 2 tiles sequentially.
// LDS: buf 128*65 | wge 64 | g2 64 | ovec 256 | [lpark 128*65 if !WSPARK]
template<bool WSPARK>
__global__ __launch_bounds__(64) void k_main(
    const float* __restrict__ x,
    const float* __restrict__ We1, const float* __restrict__ be1,
    const float* __restrict__ We2, const float* __restrict__ be2,
    const float* __restrict__ We3, const float* __restrict__ be3,
    const float* __restrict__ Wh1, const float* __restrict__ Wh2,
    const float* __restrict__ Wh3, const float* __restrict__ Wah,
    const float* __restrict__ Wte, const float* __restrict__ bte,
    const float* __restrict__ Wth, const float* __restrict__ bth,
    const float* __restrict__ Wf1, const float* __restrict__ bf1,
    const float* __restrict__ Wf2, const float* __restrict__ bf2,
    const float* __restrict__ ws, float* __restrict__ park,
    float* __restrict__ out){
  extern __shared__ float lds[];
  float* buf   = lds;            // 128*65 = 8320
  float* wge_a = lds + 8320;     // 64
  float* g2_a  = lds + 8384;     // 64
  float* ovec  = lds + 8448;     // 256
  float* lpark = lds + 8704;     // 128*65 (only when !WSPARK)
  const int t = threadIdx.x, b = blockIdx.x;

  const float* u1  = ws;         // 128
  const float* u2  = ws + 128;   // 128
  const float* eb1 = ws + 256;   // 80
  const float* eb2 = ws + 336;   // 104
  const float* eb3 = ws + 440;   // 128
  const float* eba = ws + 568;   // 128

  float poe0=0.f, poe1=0.f, poh0=0.f, poh1=0.f;

  for(int tile=0; tile<2; ++tile){
    const int s0 = tile*64;
    float* pk = WSPARK ? (park + (((size_t)(b*2+tile))<<13)) : lpark;

    // ---- load raw token x0[32] (coalesced) + expmap0 scalars ----
    float x0[32];
#pragma unroll
    for(int c=0;c<32;++c) x0[c] = x[((size_t)b*32 + c)*128 + s0 + t];
    float n2 = 0.f;
#pragma unroll
    for(int c=0;c<32;++c) n2 = fmaf(x0[c],x0[c],n2);
    float n0  = fmaxf(sqrtf(n2), MINN);
    float th0 = tanh_(SQC*n0);
    float nh  = th0/SQC;
    float scl = th0/(SQC*n0);
    if(nh > MAXN){ scl *= MAXN/nh; nh = MAXN; }

    // ---- H1: 32->80 (input scale folded), mob_relu ----
    float tau1, nf1;
    {
      float m2=0.f, meb=0.f;
      mvraw<32,80>(Wh1, eb1, x0, buf, t, m2, meb);
      m2 *= scl*scl; meb *= scl;
      HS h = hyper_chain(m2, meb, nh, ws[698]);
      float nvc = fmaxf(h.nv, MINN);
      float lam = art_(SQC*nvc)/(SQC*nvc);
      float rn2 = relu_pass<80>(buf, t, eb1, h.ca*scl, h.cb, lam);
      float rn  = fmaxf(sqrtf(rn2), MINN);
      float th  = tanh_(SQC*rn);
      tau1 = th/(SQC*rn); nf1 = th/SQC;
      if(nf1 > MAXN){ tau1 *= MAXN/nf1; nf1 = MAXN; }
    }
    float xh1[80]; loadbuf<80>(xh1, buf, t, tau1);

    // ---- H2: 80->104, mob_relu ----
    float tau2, nf2;
    {
      float m2=0.f, meb=0.f;
      mvraw<80,104>(Wh2, eb2, xh1, buf, t, m2, meb);
      HS h = hyper_chain(m2, meb, nf1, ws[699]);
      float nvc = fmaxf(h.nv, MINN);
      float lam = art_(SQC*nvc)/(SQC*nvc);
      float rn2 = relu_pass<104>(buf, t, eb2, h.ca, h.cb, lam);
      float rn  = fmaxf(sqrtf(rn2), MINN);
      float th  = tanh_(SQC*rn);
      tau2 = th/(SQC*rn); nf2 = th/SQC;
      if(nf2 > MAXN){ tau2 *= MAXN/nf2; nf2 = MAXN; }
    }
    float xh2[104]; loadbuf<104>(xh2, buf, t, tau2);

    // ---- H3: 104->128, no relu -> out_h (buf + park) ----
    float xnh, rr;
    {
      float m2=0.f, meb=0.f;
      mvraw<104,128>(Wh3, eb3, xh2, buf, t, m2, meb);
      HS h = hyper_chain(m2, meb, nf2, ws[700]);
      if(WSPARK) final_pass<128,64>(buf, t, eb3, h.ca, h.cb, pk);
      else       final_pass<128,65>(buf, t, eb3, h.ca, h.cb, pk);
      xnh = fmaxf(h.nv, MINN);
      rr  = art_(SQC*xnh);
    }

    // ---- Wah streaming pass: 4 scalars from mx = Wah . out_h ----
    float th_wte, th_wth;
    {
      float oh[128];
#pragma unroll
      for(int k=0;k<128;++k) oh[k] = buf[k*65+t];
      float m2a=0.f, mw1=0.f, mw2=0.f, meba=0.f;
      for(int jc=0;jc<128;jc+=4){
        const float* w0 = Wah + (size_t)jc*128;
        const float* w1 = w0 + 128;
        const float* w2 = w1 + 128;
        const float* w3 = w2 + 128;
        float a0=0.f,a1=0.f,a2=0.f,a3=0.f;
#pragma unroll
        for(int k=0;k<128;++k){
          const float xv = oh[k];
          a0 = fmaf(w0[k],xv,a0); a1 = fmaf(w1[k],xv,a1);
          a2 = fmaf(w2[k],xv,a2); a3 = fmaf(w3[k],xv,a3);
        }
        m2a  = fmaf(a3,a3,       fmaf(a2,a2,       fmaf(a1,a1,       fmaf(a0,a0,       m2a))));
        mw1  = fmaf(a3,Wte[jc+3],fmaf(a2,Wte[jc+2],fmaf(a1,Wte[jc+1],fmaf(a0,Wte[jc+0],mw1))));
        mw2  = fmaf(a3,Wth[jc+3],fmaf(a2,Wth[jc+2],fmaf(a1,Wth[jc+1],fmaf(a0,Wth[jc+0],mw2))));
        meba = fmaf(a3,eba[jc+3],fmaf(a2,eba[jc+2],fmaf(a1,eba[jc+1],fmaf(a0,eba[jc+0],meba))));
      }
      // tan_h dot products (p_linear on out_h then logmap0), folded
      float mxn = fmaxf(sqrtf(m2a), MINN);
      float s   = tanh_(mxn/xnh*rr)/(mxn*SQC);
      float nr  = s*mxn;
      if(nr > MAXN){ s *= MAXN/nr; nr = MAXN; }
      float xy = s*meba, x2 = nr*nr, y2 = ws[701];
      float den = fmaxf(1.f + 2.f*CC*xy + CC*CC*x2*y2, MINN);
      float A   = (1.f + 2.f*CC*xy + CC*y2)/den;
      float Bc  = (1.f - CC*x2)/den;
      float n3  = sqrtf(fmaxf(A*A*x2 + 2.f*A*Bc*xy + Bc*Bc*y2, 0.f));
      float rho = (n3 > MAXN) ? MAXN/n3 : 1.f;
      float nv  = fminf(n3, MAXN);
      float nvc = fmaxf(nv, MINN);
      float lam = art_(SQC*nvc)/(SQC*nvc);
      float lr  = lam*rho;
      th_wte = lr*(A*s*mw1 + Bc*ws[702]);
      th_wth = lr*(A*s*mw2 + Bc*ws[703]);
    }

    // ---- E branch: relu((W x + b)) x3; dots with u1,u2 at E3 ----
    float d1=0.f, d2=0.f;
    {
      float dd1=0.f, dd2=0.f;
      mveuc<32,80,false>(We1, be1, x0, buf, t, u1, u2, dd1, dd2);
      float xe1[80]; loadbuf<80>(xe1, buf, t, 1.0f);
      mveuc<80,104,false>(We2, be2, xe1, buf, t, u1, u2, dd1, dd2);
      float xe2[104]; loadbuf<104>(xe2, buf, t, 1.0f);
      mveuc<104,128,true>(We3, be3, xe2, buf, t, u1, u2, d1, d2);
    }

    // ---- attention finalize per token ----
    {
      float te1 = d1 + ws[696];
      float te2 = d2 + ws[697];
      float a_e = 0.5f*(te1 - th_wte) + bte[0];
      float a_h = 0.5f*(th_wth - te2) + bth[0];
      float mx_ = fmaxf(a_e, a_h);
      float ee = __expf(a_e - mx_), eh = __expf(a_h - mx_);
      float inv = 1.f/(ee + eh);
      float wge = ee*inv, wgh = eh*inv;
      // mobius scalar mul by wgh then logmap0 -> scalar g2 on out_h
      float inner = wgh * rr;
      float scl2  = tanh_(inner)/(xnh*SQC);
      float nn    = scl2*xnh;
      if(nn > MAXN){ scl2 *= MAXN/nn; nn = MAXN; }
      float nnc  = fmaxf(nn, MINN);
      float lam2 = art_(SQC*nnc)/(SQC*nnc);
      wge_a[t] = wge;
      g2_a[t]  = lam2*scl2;
    }

    // ---- pooled accumulation (thread handles j=t and j=t+64) ----
    for(int tt=0;tt<64;++tt){
      float wg = wge_a[tt], g = g2_a[tt];
      poe0 = fmaf(wg, buf[t*65+tt], poe0);
      poe1 = fmaf(wg, buf[(t+64)*65+tt], poe1);
      float h0, h1;
      if(WSPARK){ h0 = pk[(size_t)t*64+tt];  h1 = pk[(size_t)(t+64)*64+tt]; }
      else      { h0 = lpark[t*65+tt];       h1 = lpark[(t+64)*65+tt]; }
      poh0 = fmaf(g, h0, poh0);
      poh1 = fmaf(g, h1, poh1);
    }
  } // tile loop

  // ---- classifier (single wave) ----
  const float inv128 = 1.f/128.f;
  ovec[t]       = poe0*inv128;
  ovec[t+64]    = poe1*inv128;
  ovec[128+t]   = poh0*inv128;
  ovec[192+t]   = poh1*inv128;
  float f1v[10];
#pragma unroll
  for(int i=0;i<10;++i){
    float p = 0.f;
#pragma unroll
    for(int m=0;m<4;++m){ int k = t + 64*m; p = fmaf(Wf1[i*256+k], ovec[k], p); }
    f1v[i] = fmaxf(wsum(p) + bf1[i], 0.f);
  }
  if(t < 10){
    float o2 = bf2[t];
#pragma unroll
    for(int k=0;k<10;++k) o2 = fmaf(Wf2[t*10+k], f1v[k], o2);
    out[b*10 + t] = o2;
  }
}

extern "C" void kernel_launch(void* const* d_in, const int* in_sizes, int n_in,
                              void* d_out, int out_size, void* d_ws, size_t ws_size,
                              hipStream_t stream){
  (void)in_sizes; (void)n_in; (void)out_size;
  const float* x   = (const float*)d_in[0];
  const float* We1 = (const float*)d_in[1];
  const float* be1 = (const float*)d_in[2];
  const float* We2 = (const float*)d_in[3];
  const float* be2 = (const float*)d_in[4];
  const float* We3 = (const float*)d_in[5];
  const float* be3 = (const float*)d_in[6];
  const float* Wh1 = (const float*)d_in[7];
  const float* bh1 = (const float*)d_in[8];
  const float* Wh2 = (const float*)d_in[9];
  const float* bh2 = (const float*)d_in[10];
  const float* Wh3 = (const float*)d_in[11];
  const float* bh3 = (const float*)d_in[12];
  const float* Wae = (const float*)d_in[13];
  const float* bae = (const float*)d_in[14];
  const float* Wah = (const float*)d_in[15];
  const float* bah = (const float*)d_in[16];
  const float* Wte = (const float*)d_in[17];
  const float* bte = (const float*)d_in[18];
  const float* Wth = (const float*)d_in[19];
  const float* bth = (const float*)d_in[20];
  const float* Wf1 = (const float*)d_in[21];
  const float* bf1 = (const float*)d_in[22];
  const float* Wf2 = (const float*)d_in[23];
  const float* bf2 = (const float*)d_in[24];
  float* ws  = (float*)d_ws;
  float* out = (float*)d_out;

  hipLaunchKernelGGL(k_setup, dim3(1), dim3(256), 0, stream,
                     Wae, bae, bh1, bh2, bh3, bah, Wte, Wth, ws);

  // park region needs 1024 rows * 2 tiles * 128 j * 64 t floats after ws[1024]
  const size_t need = (1024ull + 1024ull*2*128*64) * 4ull;
  if(ws_size >= need){
    const int smem = 8704*4;
    hipFuncSetAttribute((const void*)k_main<true>,
                        hipFuncAttributeMaxDynamicSharedMemorySize, smem);
    hipLaunchKernelGGL((k_main<true>), dim3(1024), dim3(64), smem, stream,
                       x, We1,be1, We2,be2, We3,be3, Wh1,Wh2,Wh3, Wah,
                       Wte,bte, Wth,bth, Wf1,bf1, Wf2,bf2, ws, ws+1024, out);
  } else {
    const int smem = (8704+8320)*4;
    hipFuncSetAttribute((const void*)k_main<false>,
                        hipFuncAttributeMaxDynamicSharedMemorySize, smem);
    hipLaunchKernelGGL((k_main<false>), dim3(1024), dim3(64), smem, stream,
                       x, We1,be1, We2,be2, We3,be3, Wh1,Wh2,Wh3, Wah,
                       Wte,bte, Wth,bth, Wf1,bf1, Wf2,bf2, ws, (float*)nullptr, out);
  }
}

// Round 3
// 716.245 us; speedup vs baseline: 2.0504x; 1.7040x over previous
//
#include <hip/hip_runtime.h>
#include <math.h>

constexpr float CC   = 1.2f;
constexpr float SQC  = 1.09544511501033215f;      // sqrt(1.2)
constexpr float MAXN = (1.0f - 4e-3f) / SQC;      // geoopt projx maxnorm
constexpr float MINN = 1e-15f;

// ---------------- fast per-lane scalar math ----------------
__device__ __forceinline__ float art_(float x){
  x = fminf(fmaxf(x, -0.9999999f), 0.9999999f);
  return 0.5f * __logf((1.0f + x) / (1.0f - x));
}
__device__ __forceinline__ float tanh_(float x){
  x = fminf(fmaxf(x, -15.0f), 15.0f);
  float e = __expf(2.0f * x);
  return (e - 1.0f) / (e + 1.0f);
}
__device__ __forceinline__ float wsum(float v){
#pragma unroll
  for(int i=32;i>0;i>>=1) v += __shfl_xor(v, i, 64);
  return v;
}

// ---------------- setup kernel: folded constants into ws ----------------
// ws layout: [0..127] u1=Wae^T Wte, [128..255] u2=Wae^T Wth, [256..335] ebh1,
// [336..439] ebh2, [440..567] ebh3, [568..695] ebah, [696] c1 [697] c2
// [698..701] y2h1,y2h2,y2h3,y2ah, [702] EBW1 [703] EBW2.  Park region: ws+1024.
__global__ void k_setup(const float* __restrict__ Wae, const float* __restrict__ bae,
                        const float* __restrict__ bh1, const float* __restrict__ bh2,
                        const float* __restrict__ bh3, const float* __restrict__ bah,
                        const float* __restrict__ Wte, const float* __restrict__ Wth,
                        float* __restrict__ ws){
  const int tid = threadIdx.x;            // 256 threads, 1 block
  {
    const int which = tid >> 7, k = tid & 127;
    const float* wv = which ? Wth : Wte;
    float s = 0.f;
#pragma unroll 4
    for(int j=0;j<128;++j) s += Wae[j*128+k] * wv[j];
    ws[which*128 + k] = s;
  }
  if(tid < 64){
    const int l = tid;
    float p1=0.f, p2=0.f;
    for(int j=l;j<128;j+=64){ p1 += bae[j]*Wte[j]; p2 += bae[j]*Wth[j]; }
    p1 = wsum(p1); p2 = wsum(p2);
    if(l==0){ ws[696]=p1; ws[697]=p2; }
    const float* bs[4] = {bh1,bh2,bh3,bah};
    const int dims[4]  = {80,104,128,128};
    const int offs[4]  = {256,336,440,568};
    for(int v=0;v<4;++v){
      const float* bp = bs[v]; const int D = dims[v];
      float q = 0.f;
      for(int j=l;j<D;j+=64) q += bp[j]*bp[j];
      q = wsum(q);
      float nb = fmaxf(sqrtf(q), MINN);
      float th = tanhf(fminf(fmaxf(SQC*nb,-15.f),15.f));
      float coef = th/(SQC*nb);
      float ne = th/SQC;
      if(ne > MAXN){ coef *= MAXN/ne; ne = MAXN; }
      for(int j=l;j<D;j+=64) ws[offs[v]+j] = coef*bp[j];
      if(l==0) ws[698+v] = ne*ne;
      if(v==3){
        float e1=0.f, e2=0.f;
        for(int j=l;j<D;j+=64){ e1 += bp[j]*Wte[j]; e2 += bp[j]*Wth[j]; }
        e1 = wsum(e1)*coef; e2 = wsum(e2)*coef;
        if(l==0){ ws[702]=e1; ws[703]=e2; }
      }
    }
  }
}

// ---------------- weight streaming: global -> LDS ring (2 x 512 floats) ----
// chunk = 512 padded floats. Row stride KP (32 or 128) so 4-row groups never
// straddle the 1024-float ring and all ds_read offsets are static.
template<int K,int KP>
__device__ __forceinline__ void ldch(const float* __restrict__ W, int c, int lane,
                                     float4& r0, float4& r1){
  const int f0 = (c<<9) + (lane<<2);
  const int f1 = f0 + 256;
  if constexpr (K == KP){
    r0 = *(const float4*)(W + f0);
    r1 = *(const float4*)(W + f1);
  } else {
    const int row0 = f0 >> 7, col0 = f0 & 127;
    const int row1 = f1 >> 7, col1 = f1 & 127;
    r0 = (col0 < K) ? *(const float4*)(W + row0*K + col0) : make_float4(0.f,0.f,0.f,0.f);
    r1 = (col1 < K) ? *(const float4*)(W + row1*K + col1) : make_float4(0.f,0.f,0.f,0.f);
  }
}

__device__ __forceinline__ void commit(float* __restrict__ ring, int c, int lane,
                                       const float4& r0, const float4& r1){
  float* dst = ring + ((c & 1) << 9);
  *(float4*)(dst + (lane<<2)) = r0;
  *(float4*)(dst + 256 + (lane<<2)) = r1;
}

// stream all OUT rows of W (4 at a time), FMA against reg-resident xin,
// hand each group of 4 outputs to sink(jb, a0..a3).
template<int K,int KP,int OUT,typename F>
__device__ __forceinline__ void stream_mv(const float* __restrict__ W,
                                          float* __restrict__ ring, int lane,
                                          const float (&xin)[K], F&& sink){
  constexpr int NCH = (OUT*KP) >> 9;   // chunks (always exact, >=5... >=2)
  constexpr int NG  = OUT >> 2;        // 4-row groups
  float4 p0,p1,q0,q1;
  ldch<K,KP>(W, 0, lane, p0, p1);
  ldch<K,KP>(W, 1, lane, q0, q1);
  commit(ring, 0, lane, p0, p1);
  int cm = 0;          // last committed chunk
  int nl = 2;          // next chunk to load
  for(int g=0; g<NG; ++g){
    const int need = ((g+1)*(4*KP) - 1) >> 9;
    if(cm < need){
      ++cm;
      commit(ring, cm, lane, q0, q1);   // s_waitcnt on q's loads (issued 1 chunk ago)
      if(nl < NCH) ldch<K,KP>(W, nl, lane, q0, q1);
      ++nl;
    }
    const float* rg = ring + ((g*(4*KP)) & 1023);
    float a0=0.f,a1=0.f,a2=0.f,a3=0.f;
#pragma unroll
    for(int k=0;k<K;k+=4){
      float4 w0 = *(const float4*)(rg + 0*KP + k);
      float4 w1 = *(const float4*)(rg + 1*KP + k);
      float4 w2 = *(const float4*)(rg + 2*KP + k);
      float4 w3 = *(const float4*)(rg + 3*KP + k);
      const float xa=xin[k], xb=xin[k+1], xc=xin[k+2], xd=xin[k+3];
      a0 = fmaf(w0.w,xd, fmaf(w0.z,xc, fmaf(w0.y,xb, fmaf(w0.x,xa, a0))));
      a1 = fmaf(w1.w,xd, fmaf(w1.z,xc, fmaf(w1.y,xb, fmaf(w1.x,xa, a1))));
      a2 = fmaf(w2.w,xd, fmaf(w2.z,xc, fmaf(w2.y,xb, fmaf(w2.x,xa, a2))));
      a3 = fmaf(w3.w,xd, fmaf(w3.z,xc, fmaf(w3.y,xb, fmaf(w3.x,xa, a3))));
    }
    sink(g<<2, a0, a1, a2, a3);
  }
}

// Mobius matvec+bias scalar chain (per-lane)
struct HS { float ca, cb, nv; };
__device__ __forceinline__ HS hyper_chain(float m2, float meb, float xn_in, float y2){
  float xn  = fmaxf(xn_in, MINN);
  float mxn = fmaxf(sqrtf(m2), MINN);
  float r   = art_(SQC*xn);
  float s   = tanh_(mxn/xn*r)/(mxn*SQC);
  float nr  = s*mxn;
  if(nr > MAXN){ s *= MAXN/nr; nr = MAXN; }
  float xy = s*meb, x2 = nr*nr;
  float den = fmaxf(1.f + 2.f*CC*xy + CC*CC*x2*y2, MINN);
  float A   = (1.f + 2.f*CC*xy + CC*y2)/den;
  float Bc  = (1.f - CC*x2)/den;
  float n3  = sqrtf(fmaxf(A*A*x2 + 2.f*A*Bc*xy + Bc*Bc*y2, 0.f));
  float rho = (n3 > MAXN) ? MAXN/n3 : 1.f;
  HS h; h.nv = fminf(n3, MAXN); h.ca = rho*A*s; h.cb = rho*Bc;
  return h;
}

// ---------------- LDS layout (floats) ----------------
constexpr int L_BUF  = 0;        // 128 x 65 activation scratch (lane-private, stride 65 for pooling)
constexpr int L_RING = 8320;     // 1024-float weight ring
constexpr int L_WGE  = 9344;     // 64
constexpr int L_G2   = 9408;     // 64
constexpr int L_OVEC = 9472;     // 256
constexpr int L_TOT  = 9728;     // 38,912 B -> 4 blocks/CU

// ---------------- main kernel: 1 block = 1 wave = one batch row ----------------
template<bool WSPARK>
__global__ __launch_bounds__(64) void k_main(
    const float* __restrict__ x,
    const float* __restrict__ We1, const float* __restrict__ be1,
    const float* __restrict__ We2, const float* __restrict__ be2,
    const float* __restrict__ We3, const float* __restrict__ be3,
    const float* __restrict__ Wh1, const float* __restrict__ Wh2,
    const float* __restrict__ Wh3, const float* __restrict__ Wah,
    const float* __restrict__ Wte, const float* __restrict__ bte,
    const float* __restrict__ Wth, const float* __restrict__ bth,
    const float* __restrict__ Wf1, const float* __restrict__ bf1,
    const float* __restrict__ Wf2, const float* __restrict__ bf2,
    const float* __restrict__ ws, float* __restrict__ park,
    float* __restrict__ out){
  extern __shared__ float lds[];
  float* buf   = lds + L_BUF;
  float* ring  = lds + L_RING;
  float* wge_a = lds + L_WGE;
  float* g2_a  = lds + L_G2;
  float* ovec  = lds + L_OVEC;
  float* lpark = lds + L_TOT;          // only when !WSPARK (extra 8320 floats)
  const int t = threadIdx.x, b = blockIdx.x;
  constexpr int PSTR = WSPARK ? 64 : 65;

  const float* u1  = ws;         // 128
  const float* u2  = ws + 128;   // 128
  const float* eb1 = ws + 256;   // 80
  const float* eb2 = ws + 336;   // 104
  const float* eb3 = ws + 440;   // 128
  const float* eba = ws + 568;   // 128

  float poe0=0.f, poe1=0.f, poh0=0.f, poh1=0.f;

  for(int tile=0; tile<2; ++tile){
    const int s0 = tile*64;
    float* pk = WSPARK ? (park + (((size_t)(b*2+tile))<<13)) : lpark;

    // ---- token input + expmap0 scalars ----
    float x0[32];
#pragma unroll
    for(int c=0;c<32;++c) x0[c] = x[((size_t)b*32 + c)*128 + s0 + t];
    float n2 = 0.f;
#pragma unroll
    for(int c=0;c<32;++c) n2 = fmaf(x0[c],x0[c],n2);
    float n0  = fmaxf(sqrtf(n2), MINN);
    float th0 = tanh_(SQC*n0);
    float nh  = th0/SQC;
    float scl = th0/(SQC*n0);
    if(nh > MAXN){ scl *= MAXN/nh; nh = MAXN; }

    // ---- H1: 32->80 (input scale folded), mob_relu ----
    float xh1[80]; float nf1;
    {
      float m2=0.f, meb=0.f;
      stream_mv<32,32,80>(Wh1, ring, t, x0, [&](int jb,float a0,float a1,float a2,float a3){
        buf[(jb+0)*65+t]=a0; buf[(jb+1)*65+t]=a1; buf[(jb+2)*65+t]=a2; buf[(jb+3)*65+t]=a3;
        m2  = fmaf(a3,a3,      fmaf(a2,a2,      fmaf(a1,a1,      fmaf(a0,a0,      m2))));
        meb = fmaf(a3,eb1[jb+3],fmaf(a2,eb1[jb+2],fmaf(a1,eb1[jb+1],fmaf(a0,eb1[jb],meb))));
      });
      m2 *= scl*scl; meb *= scl;
      HS h = hyper_chain(m2, meb, nh, ws[698]);
      float nvc = fmaxf(h.nv, MINN);
      float lam = art_(SQC*nvc)/(SQC*nvc);
      float ca = h.ca*scl, cb = h.cb;
      float r[80]; float rn2 = 0.f;
#pragma unroll
      for(int j=0;j<80;++j){
        float v = fmaf(ca, buf[j*65+t], cb*eb1[j]);
        r[j] = fmaxf(lam*v, 0.f);
        rn2 = fmaf(r[j],r[j],rn2);
      }
      float rn = fmaxf(sqrtf(rn2), MINN);
      float th = tanh_(SQC*rn);
      float tau = th/(SQC*rn); nf1 = th/SQC;
      if(nf1 > MAXN){ tau *= MAXN/nf1; nf1 = MAXN; }
#pragma unroll
      for(int j=0;j<80;++j) xh1[j] = tau*r[j];
    }

    // ---- H2: 80->104, mob_relu ----
    float xh2[104]; float nf2;
    {
      float m2=0.f, meb=0.f;
      stream_mv<80,128,104>(Wh2, ring, t, xh1, [&](int jb,float a0,float a1,float a2,float a3){
        buf[(jb+0)*65+t]=a0; buf[(jb+1)*65+t]=a1; buf[(jb+2)*65+t]=a2; buf[(jb+3)*65+t]=a3;
        m2  = fmaf(a3,a3,      fmaf(a2,a2,      fmaf(a1,a1,      fmaf(a0,a0,      m2))));
        meb = fmaf(a3,eb2[jb+3],fmaf(a2,eb2[jb+2],fmaf(a1,eb2[jb+1],fmaf(a0,eb2[jb],meb))));
      });
      HS h = hyper_chain(m2, meb, nf1, ws[699]);
      float nvc = fmaxf(h.nv, MINN);
      float lam = art_(SQC*nvc)/(SQC*nvc);
      float r[104]; float rn2 = 0.f;
#pragma unroll
      for(int j=0;j<104;++j){
        float v = fmaf(h.ca, buf[j*65+t], h.cb*eb2[j]);
        r[j] = fmaxf(lam*v, 0.f);
        rn2 = fmaf(r[j],r[j],rn2);
      }
      float rn = fmaxf(sqrtf(rn2), MINN);
      float th = tanh_(SQC*rn);
      float tau = th/(SQC*rn); nf2 = th/SQC;
      if(nf2 > MAXN){ tau *= MAXN/nf2; nf2 = MAXN; }
#pragma unroll
      for(int j=0;j<104;++j) xh2[j] = tau*r[j];
    }

    // ---- H3: 104->128 (no relu) -> oh regs + park; then Wah scalar pass ----
    float xnh, rr, th_wte, th_wth;
    {
      float m2=0.f, meb=0.f;
      stream_mv<104,128,128>(Wh3, ring, t, xh2, [&](int jb,float a0,float a1,float a2,float a3){
        buf[(jb+0)*65+t]=a0; buf[(jb+1)*65+t]=a1; buf[(jb+2)*65+t]=a2; buf[(jb+3)*65+t]=a3;
        m2  = fmaf(a3,a3,      fmaf(a2,a2,      fmaf(a1,a1,      fmaf(a0,a0,      m2))));
        meb = fmaf(a3,eb3[jb+3],fmaf(a2,eb3[jb+2],fmaf(a1,eb3[jb+1],fmaf(a0,eb3[jb],meb))));
      });
      HS h = hyper_chain(m2, meb, nf2, ws[700]);
      float oh[128];
#pragma unroll
      for(int j=0;j<128;++j){
        oh[j] = fmaf(h.ca, buf[j*65+t], h.cb*eb3[j]);
        pk[(size_t)j*PSTR + t] = oh[j];
      }
      xnh = fmaxf(h.nv, MINN);
      rr  = art_(SQC*xnh);

      float m2a=0.f, mw1=0.f, mw2=0.f, meba=0.f;
      stream_mv<128,128,128>(Wah, ring, t, oh, [&](int jb,float a0,float a1,float a2,float a3){
        m2a  = fmaf(a3,a3,        fmaf(a2,a2,        fmaf(a1,a1,        fmaf(a0,a0,        m2a))));
        mw1  = fmaf(a3,Wte[jb+3], fmaf(a2,Wte[jb+2], fmaf(a1,Wte[jb+1], fmaf(a0,Wte[jb],  mw1))));
        mw2  = fmaf(a3,Wth[jb+3], fmaf(a2,Wth[jb+2], fmaf(a1,Wth[jb+1], fmaf(a0,Wth[jb],  mw2))));
        meba = fmaf(a3,eba[jb+3], fmaf(a2,eba[jb+2], fmaf(a1,eba[jb+1], fmaf(a0,eba[jb],  meba))));
      });
      float mxn = fmaxf(sqrtf(m2a), MINN);
      float s   = tanh_(mxn/xnh*rr)/(mxn*SQC);
      float nr  = s*mxn;
      if(nr > MAXN){ s *= MAXN/nr; nr = MAXN; }
      float xy = s*meba, x2 = nr*nr, y2 = ws[701];
      float den = fmaxf(1.f + 2.f*CC*xy + CC*CC*x2*y2, MINN);
      float A   = (1.f + 2.f*CC*xy + CC*y2)/den;
      float Bc  = (1.f - CC*x2)/den;
      float n3  = sqrtf(fmaxf(A*A*x2 + 2.f*A*Bc*xy + Bc*Bc*y2, 0.f));
      float rho = (n3 > MAXN) ? MAXN/n3 : 1.f;
      float nv  = fminf(n3, MAXN);
      float nvc = fmaxf(nv, MINN);
      float lam = art_(SQC*nvc)/(SQC*nvc);
      float lr  = lam*rho;
      th_wte = lr*(A*s*mw1 + Bc*ws[702]);
      th_wth = lr*(A*s*mw2 + Bc*ws[703]);
    }

    // ---- E branch ----
    float d1=0.f, d2=0.f;
    {
      stream_mv<32,32,80>(We1, ring, t, x0, [&](int jb,float a0,float a1,float a2,float a3){
        buf[(jb+0)*65+t]=fmaxf(a0+be1[jb  ],0.f);
        buf[(jb+1)*65+t]=fmaxf(a1+be1[jb+1],0.f);
        buf[(jb+2)*65+t]=fmaxf(a2+be1[jb+2],0.f);
        buf[(jb+3)*65+t]=fmaxf(a3+be1[jb+3],0.f);
      });
      float xe1[80];
#pragma unroll
      for(int j=0;j<80;++j) xe1[j] = buf[j*65+t];

      stream_mv<80,128,104>(We2, ring, t, xe1, [&](int jb,float a0,float a1,float a2,float a3){
        buf[(jb+0)*65+t]=fmaxf(a0+be2[jb  ],0.f);
        buf[(jb+1)*65+t]=fmaxf(a1+be2[jb+1],0.f);
        buf[(jb+2)*65+t]=fmaxf(a2+be2[jb+2],0.f);
        buf[(jb+3)*65+t]=fmaxf(a3+be2[jb+3],0.f);
      });
      float xe2[104];
#pragma unroll
      for(int j=0;j<104;++j) xe2[j] = buf[j*65+t];

      stream_mv<104,128,128>(We3, ring, t, xe2, [&](int jb,float a0,float a1,float a2,float a3){
        float v0=fmaxf(a0+be3[jb  ],0.f);
        float v1=fmaxf(a1+be3[jb+1],0.f);
        float v2=fmaxf(a2+be3[jb+2],0.f);
        float v3=fmaxf(a3+be3[jb+3],0.f);
        buf[(jb+0)*65+t]=v0; buf[(jb+1)*65+t]=v1;
        buf[(jb+2)*65+t]=v2; buf[(jb+3)*65+t]=v3;
        d1 = fmaf(v3,u1[jb+3],fmaf(v2,u1[jb+2],fmaf(v1,u1[jb+1],fmaf(v0,u1[jb],d1))));
        d2 = fmaf(v3,u2[jb+3],fmaf(v2,u2[jb+2],fmaf(v1,u2[jb+1],fmaf(v0,u2[jb],d2))));
      });
    }

    // ---- attention finalize per token ----
    {
      float te1 = d1 + ws[696];
      float te2 = d2 + ws[697];
      float a_e = 0.5f*(te1 - th_wte) + bte[0];
      float a_h = 0.5f*(th_wth - te2) + bth[0];
      float mx_ = fmaxf(a_e, a_h);
      float ee = __expf(a_e - mx_), eh = __expf(a_h - mx_);
      float inv = 1.f/(ee + eh);
      float wge = ee*inv, wgh = eh*inv;
      float inner = wgh * rr;
      float scl2  = tanh_(inner)/(xnh*SQC);
      float nn    = scl2*xnh;
      if(nn > MAXN){ scl2 *= MAXN/nn; nn = MAXN; }
      float nnc  = fmaxf(nn, MINN);
      float lam2 = art_(SQC*nnc)/(SQC*nnc);
      wge_a[t] = wge;
      g2_a[t]  = lam2*scl2;
    }

    // ---- pooled accumulation (thread t handles j=t and j=t+64) ----
    for(int tt=0;tt<64;++tt){
      float wg = wge_a[tt], g = g2_a[tt];
      poe0 = fmaf(wg, buf[t*65+tt], poe0);
      poe1 = fmaf(wg, buf[(t+64)*65+tt], poe1);
      float h0, h1;
      if(WSPARK){ h0 = pk[(size_t)t*64+tt];  h1 = pk[(size_t)(t+64)*64+tt]; }
      else      { h0 = lpark[t*65+tt];       h1 = lpark[(t+64)*65+tt]; }
      poh0 = fmaf(g, h0, poh0);
      poh1 = fmaf(g, h1, poh1);
    }
  } // tile loop

  // ---- classifier (single wave) ----
  const float inv128 = 1.f/128.f;
  ovec[t]       = poe0*inv128;
  ovec[t+64]    = poe1*inv128;
  ovec[128+t]   = poh0*inv128;
  ovec[192+t]   = poh1*inv128;
  float f1v[10];
#pragma unroll
  for(int i=0;i<10;++i){
    float p = 0.f;
#pragma unroll
    for(int m=0;m<4;++m){ int k = t + 64*m; p = fmaf(Wf1[i*256+k], ovec[k], p); }
    f1v[i] = fmaxf(wsum(p) + bf1[i], 0.f);
  }
  if(t < 10){
    float o2 = bf2[t];
#pragma unroll
    for(int k=0;k<10;++k) o2 = fmaf(Wf2[t*10+k], f1v[k], o2);
    out[b*10 + t] = o2;
  }
}

extern "C" void kernel_launch(void* const* d_in, const int* in_sizes, int n_in,
                              void* d_out, int out_size, void* d_ws, size_t ws_size,
                              hipStream_t stream){
  (void)in_sizes; (void)n_in; (void)out_size;
  const float* x   = (const float*)d_in[0];
  const float* We1 = (const float*)d_in[1];
  const float* be1 = (const float*)d_in[2];
  const float* We2 = (const float*)d_in[3];
  const float* be2 = (const float*)d_in[4];
  const float* We3 = (const float*)d_in[5];
  const float* be3 = (const float*)d_in[6];
  const float* Wh1 = (const float*)d_in[7];
  const float* bh1 = (const float*)d_in[8];
  const float* Wh2 = (const float*)d_in[9];
  const float* bh2 = (const float*)d_in[10];
  const float* Wh3 = (const float*)d_in[11];
  const float* bh3 = (const float*)d_in[12];
  const float* Wae = (const float*)d_in[13];
  const float* bae = (const float*)d_in[14];
  const float* Wah = (const float*)d_in[15];
  const float* bah = (const float*)d_in[16];
  const float* Wte = (const float*)d_in[17];
  const float* bte = (const float*)d_in[18];
  const float* Wth = (const float*)d_in[19];
  const float* bth = (const float*)d_in[20];
  const float* Wf1 = (const float*)d_in[21];
  const float* bf1 = (const float*)d_in[22];
  const float* Wf2 = (const float*)d_in[23];
  const float* bf2 = (const float*)d_in[24];
  float* ws  = (float*)d_ws;
  float* out = (float*)d_out;

  hipLaunchKernelGGL(k_setup, dim3(1), dim3(256), 0, stream,
                     Wae, bae, bh1, bh2, bh3, bah, Wte, Wth, ws);

  // park region: 1024 rows * 2 tiles * 128 j * 64 t floats after ws[1024]
  const size_t need = (1024ull + 1024ull*2*128*64) * 4ull;
  if(ws_size >= need){
    const int smem = L_TOT*4;
    hipLaunchKernelGGL((k_main<true>), dim3(1024), dim3(64), smem, stream,
                       x, We1,be1, We2,be2, We3,be3, Wh1,Wh2,Wh3, Wah,
                       Wte,bte, Wth,bth, Wf1,bf1, Wf2,bf2, ws, ws+1024, out);
  } else {
    const int smem = (L_TOT+8320)*4;
    hipFuncSetAttribute((const void*)k_main<false>,
                        hipFuncAttributeMaxDynamicSharedMemorySize, smem);
    hipLaunchKernelGGL((k_main<false>), dim3(1024), dim3(64), smem, stream,
                       x, We1,be1, We2,be2, We3,be3, Wh1,Wh2,Wh3, Wah,
                       Wte,bte, Wth,bth, Wf1,bf1, Wf2,bf2, ws, (float*)nullptr, out);
  }
}